// Round 3
// baseline (793.834 us; speedup 1.0000x reference)
//
#include <hip/hip_runtime.h>

#define USER_NUM 100000
#define ITEM_NUM 100000
#define NN 200000
#define DIM 64
#define EPSV 0.2f

#define NB 196          // coarse buckets of 1024 dst-nodes (ceil(200000/1024))
#define BSH 10          // bucket = dst >> 10
#define NPB 1024        // nodes per bucket
#define CH 4096         // edges per workgroup chunk in pass A
#define PER 16          // edges per thread (256*16 = 4096)
#define SRC_MASK 0x3FFFF

// ---------------------------------------------------------------------------
// K1: coarse bucket histogram (196 counters) via LDS aggregation
// ---------------------------------------------------------------------------
__global__ __launch_bounds__(256) void bhist_k(const int* __restrict__ dst,
                                               int* __restrict__ bhist, int E) {
    __shared__ int h[NB];
    int t = threadIdx.x;
    for (int i = t; i < NB; i += 256) h[i] = 0;
    __syncthreads();
    long long base = (long long)blockIdx.x * CH;
    #pragma unroll
    for (int j = 0; j < PER; ++j) {
        long long e = base + t + j * 256;
        if (e < E) atomicAdd(&h[dst[e] >> BSH], 1);
    }
    __syncthreads();
    for (int i = t; i < NB; i += 256) if (h[i]) atomicAdd(&bhist[i], h[i]);
}

// ---------------------------------------------------------------------------
// K2: exclusive scan over 196 bucket counts (single block)
// ---------------------------------------------------------------------------
__global__ __launch_bounds__(256) void bscan_k(const int* __restrict__ bhist,
                                               int* __restrict__ bucket_base,
                                               int* __restrict__ bucket_off,
                                               int* __restrict__ row_ptr, int E) {
    __shared__ int tmp[256];
    int t = threadIdx.x;
    int s = (t < NB) ? bhist[t] : 0;
    tmp[t] = s;
    __syncthreads();
    for (int off = 1; off < 256; off <<= 1) {
        int x = (t >= off) ? tmp[t - off] : 0;
        __syncthreads();
        tmp[t] += x;
        __syncthreads();
    }
    int excl = tmp[t] - s;
    if (t < NB) { bucket_base[t] = excl; bucket_off[t] = excl; }
    if (t == 0) { bucket_base[NB] = E; row_ptr[NN] = E; }
}

// ---------------------------------------------------------------------------
// K3 (pass A): LDS multi-split into 196 bucket regions, dense run writes.
// Record: x = src | (dst&1023)<<18 ; y = val bits.
// ---------------------------------------------------------------------------
__global__ __launch_bounds__(256) void apart_k(const int* __restrict__ src,
                                               const int* __restrict__ dst,
                                               const float* __restrict__ vals,
                                               int* __restrict__ bucket_off,
                                               int2* __restrict__ out, int E) {
    __shared__ int cnt[NB], start[NB], cursor[NB], gbase[NB];
    __shared__ int tmp[256];
    __shared__ int2 rec[CH];
    int t = threadIdx.x;
    long long base = (long long)blockIdx.x * CH;
    int nvalid = (int)min((long long)CH, (long long)E - base);

    int s_[PER]; int d_[PER]; float v_[PER];
    for (int i = t; i < NB; i += 256) cnt[i] = 0;
    __syncthreads();
    #pragma unroll
    for (int j = 0; j < PER; ++j) {
        int idx = t + j * 256;
        if (idx < nvalid) {
            long long e = base + idx;
            d_[j] = dst[e]; s_[j] = src[e]; v_[j] = vals[e];
            atomicAdd(&cnt[d_[j] >> BSH], 1);
        } else d_[j] = -1;
    }
    __syncthreads();
    int c = (t < NB) ? cnt[t] : 0;
    tmp[t] = c;
    __syncthreads();
    for (int off = 1; off < 256; off <<= 1) {
        int x = (t >= off) ? tmp[t - off] : 0;
        __syncthreads();
        tmp[t] += x;
        __syncthreads();
    }
    if (t < NB) {
        int excl = tmp[t] - c;
        start[t] = excl; cursor[t] = excl;
        gbase[t] = (c > 0) ? atomicAdd(&bucket_off[t], c) : 0;
    }
    __syncthreads();
    #pragma unroll
    for (int j = 0; j < PER; ++j) {
        if (d_[j] >= 0) {
            int b = d_[j] >> BSH;
            int slot = atomicAdd(&cursor[b], 1);
            rec[slot] = make_int2(s_[j] | ((d_[j] & (NPB - 1)) << 18),
                                  __float_as_int(v_[j]));
        }
    }
    __syncthreads();
    // flush: consecutive LDS slots -> contiguous global runs per bucket
    for (int slot = t; slot < nvalid; slot += 256) {
        int lo = 0, hi = NB - 1;
        while (lo < hi) {
            int mid = (lo + hi + 1) >> 1;
            if (start[mid] <= slot) lo = mid; else hi = mid - 1;
        }
        out[gbase[lo] + (slot - start[lo])] = rec[slot];
    }
}

// ---------------------------------------------------------------------------
// K4 (pass B): one WG per bucket. Per-node hist + scan in LDS -> row_ptr,
// then scatter to final CSR position (random only within ~130KB, 1 CU).
// ---------------------------------------------------------------------------
__global__ __launch_bounds__(256) void bsort_k(const int* __restrict__ bucket_base,
                                               const int2* __restrict__ in,
                                               int2* __restrict__ out,
                                               int* __restrict__ row_ptr) {
    __shared__ int noff[NPB];
    __shared__ int tmp[256];
    int b = blockIdx.x, t = threadIdx.x;
    int rbeg = bucket_base[b], rend = bucket_base[b + 1];
    for (int i = t; i < NPB; i += 256) noff[i] = 0;
    __syncthreads();
    for (int i = rbeg + t; i < rend; i += 256)
        atomicAdd(&noff[(in[i].x >> 18) & (NPB - 1)], 1);
    __syncthreads();
    // exclusive scan of 1024 counters with 256 threads (4 each)
    int l0 = noff[t * 4], l1 = noff[t * 4 + 1], l2 = noff[t * 4 + 2], l3 = noff[t * 4 + 3];
    int s = l0 + l1 + l2 + l3;
    tmp[t] = s;
    __syncthreads();
    for (int off = 1; off < 256; off <<= 1) {
        int x = (t >= off) ? tmp[t - off] : 0;
        __syncthreads();
        tmp[t] += x;
        __syncthreads();
    }
    int run = rbeg + tmp[t] - s;
    int e0 = run, e1 = run + l0, e2 = e1 + l1, e3 = e2 + l2;
    noff[t * 4] = e0; noff[t * 4 + 1] = e1; noff[t * 4 + 2] = e2; noff[t * 4 + 3] = e3;
    int node0 = b * NPB + t * 4;
    if (node0 < NN)     row_ptr[node0]     = e0;
    if (node0 + 1 < NN) row_ptr[node0 + 1] = e1;
    if (node0 + 2 < NN) row_ptr[node0 + 2] = e2;
    if (node0 + 3 < NN) row_ptr[node0 + 3] = e3;
    __syncthreads();
    for (int i = rbeg + t; i < rend; i += 256) {
        int2 r = in[i];
        int pos = atomicAdd(&noff[(r.x >> 18) & (NPB - 1)], 1);
        out[pos] = r;
    }
}

// ---------------------------------------------------------------------------
// fused segmented SpMM + noise injection + acc.
// one 64-lane wave per dst row; 4 edge-groups x 16 lanes; lane gathers a
// float4 (4 dims) of its group's source row.
// f64 accumulation for replay-stability (CSR edge order varies across graph
// replays; sign() is discontinuous -- see round-1 failure).
// NEW: 16-edge superiteration = 4 independent {record, gather} pairs in
// flight per lane (was 2 via unroll) to cover L2/L3 gather latency.
// ---------------------------------------------------------------------------
__global__ __launch_bounds__(256) void spmm_fused_k(const int* __restrict__ row_ptr,
                                                    const int2* __restrict__ ssv,
                                                    const float* __restrict__ ego_u,
                                                    const float* __restrict__ ego_i,
                                                    float* __restrict__ ego_out,
                                                    const float* __restrict__ nz_layer,
                                                    float* __restrict__ acc,
                                                    int is_first, int is_last) {
    int node = blockIdx.x * 4 + (threadIdx.x >> 6);
    int lane = threadIdx.x & 63;
    int g    = lane >> 4;           // edge slot 0..3 within a 4-edge block
    int d4   = lane & 15;           // which float4 chunk of the 64 dims
    int beg = row_ptr[node];
    int end = row_ptr[node + 1];

    double ax = 0.0, ay = 0.0, az = 0.0, aw = 0.0;
    int base = beg;

    // 16 edges per superiteration: 4 independent record loads, then 4
    // independent float4 gathers (all can be outstanding), then 16 FMAs.
    for (; base + 16 <= end; base += 16) {
        int2 sv0 = ssv[base + g];
        int2 sv1 = ssv[base + 4 + g];
        int2 sv2 = ssv[base + 8 + g];
        int2 sv3 = ssv[base + 12 + g];
        int s0 = sv0.x & SRC_MASK, s1 = sv1.x & SRC_MASK;
        int s2 = sv2.x & SRC_MASK, s3 = sv3.x & SRC_MASK;
        const float* e0 = (s0 < USER_NUM) ? ego_u : ego_i;
        const float* e1 = (s1 < USER_NUM) ? ego_u : ego_i;
        const float* e2 = (s2 < USER_NUM) ? ego_u : ego_i;
        const float* e3 = (s3 < USER_NUM) ? ego_u : ego_i;
        const float4 r0 = *reinterpret_cast<const float4*>(e0 + ((size_t)s0 << 6) + (d4 << 2));
        const float4 r1 = *reinterpret_cast<const float4*>(e1 + ((size_t)s1 << 6) + (d4 << 2));
        const float4 r2 = *reinterpret_cast<const float4*>(e2 + ((size_t)s2 << 6) + (d4 << 2));
        const float4 r3 = *reinterpret_cast<const float4*>(e3 + ((size_t)s3 << 6) + (d4 << 2));
        double v0 = (double)__int_as_float(sv0.y);
        double v1 = (double)__int_as_float(sv1.y);
        double v2 = (double)__int_as_float(sv2.y);
        double v3 = (double)__int_as_float(sv3.y);
        ax = fma((double)r0.x, v0, ax); ay = fma((double)r0.y, v0, ay);
        az = fma((double)r0.z, v0, az); aw = fma((double)r0.w, v0, aw);
        ax = fma((double)r1.x, v1, ax); ay = fma((double)r1.y, v1, ay);
        az = fma((double)r1.z, v1, az); aw = fma((double)r1.w, v1, aw);
        ax = fma((double)r2.x, v2, ax); ay = fma((double)r2.y, v2, ay);
        az = fma((double)r2.z, v2, az); aw = fma((double)r2.w, v2, aw);
        ax = fma((double)r3.x, v3, ax); ay = fma((double)r3.y, v3, ay);
        az = fma((double)r3.z, v3, az); aw = fma((double)r3.w, v3, aw);
    }
    // 4-edge blocks
    for (; base + 4 <= end; base += 4) {
        int2 sv = ssv[base + g];
        int s = sv.x & SRC_MASK;
        double v = (double)__int_as_float(sv.y);
        const float* eb = (s < USER_NUM) ? ego_u : ego_i;
        const float4 r = *reinterpret_cast<const float4*>(eb + ((size_t)s << 6) + (d4 << 2));
        ax = fma((double)r.x, v, ax); ay = fma((double)r.y, v, ay);
        az = fma((double)r.z, v, az); aw = fma((double)r.w, v, aw);
    }
    int rem = end - base;
    if (g < rem) {
        int2 sv = ssv[base + g];
        int s = sv.x & SRC_MASK;
        double v = (double)__int_as_float(sv.y);
        const float* eb = (s < USER_NUM) ? ego_u : ego_i;
        const float4 r = *reinterpret_cast<const float4*>(eb + ((size_t)s << 6) + (d4 << 2));
        ax = fma((double)r.x, v, ax); ay = fma((double)r.y, v, ay);
        az = fma((double)r.z, v, az); aw = fma((double)r.w, v, aw);
    }
    // reduce the 4 edge groups (lane bits 4 and 5) in f64 (fixed tree order)
    ax += __shfl_xor(ax, 16, 64); ay += __shfl_xor(ay, 16, 64);
    az += __shfl_xor(az, 16, 64); aw += __shfl_xor(aw, 16, 64);
    ax += __shfl_xor(ax, 32, 64); ay += __shfl_xor(ay, 32, 64);
    az += __shfl_xor(az, 32, 64); aw += __shfl_xor(aw, 32, 64);
    float fx = (float)ax, fy = (float)ay, fz = (float)az, fw = (float)aw;

    size_t off = (size_t)node * DIM + (d4 << 2);
    const float4 nz = *reinterpret_cast<const float4*>(nz_layer + off);
    float ss = nz.x * nz.x + nz.y * nz.y + nz.z * nz.z + nz.w * nz.w;
    // reduce over the 16 dim-chunk lanes (groups hold identical copies)
    ss += __shfl_xor(ss, 1, 64);
    ss += __shfl_xor(ss, 2, 64);
    ss += __shfl_xor(ss, 4, 64);
    ss += __shfl_xor(ss, 8, 64);
    float e = EPSV / fmaxf(sqrtf(ss), 1e-12f);

    float4 val;
    val.x = fx + ((fx > 0.f) ? 1.f : ((fx < 0.f) ? -1.f : 0.f)) * nz.x * e;
    val.y = fy + ((fy > 0.f) ? 1.f : ((fy < 0.f) ? -1.f : 0.f)) * nz.y * e;
    val.z = fz + ((fz > 0.f) ? 1.f : ((fz < 0.f) ? -1.f : 0.f)) * nz.z * e;
    val.w = fw + ((fw > 0.f) ? 1.f : ((fw < 0.f) ? -1.f : 0.f)) * nz.w * e;

    if (g == 0) {
        if (!is_last) *reinterpret_cast<float4*>(ego_out + off) = val;
        float4 r4;
        if (is_first) {
            r4 = val;
        } else {
            const float4 p = *reinterpret_cast<const float4*>(acc + off);
            r4.x = p.x + val.x; r4.y = p.y + val.y;
            r4.z = p.z + val.z; r4.w = p.w + val.w;
        }
        if (is_last) {
            r4.x *= (1.0f / 3.0f); r4.y *= (1.0f / 3.0f);
            r4.z *= (1.0f / 3.0f); r4.w *= (1.0f / 3.0f);
        }
        *reinterpret_cast<float4*>(acc + off) = r4;
    }
}

extern "C" void kernel_launch(void* const* d_in, const int* in_sizes, int n_in,
                              void* d_out, int out_size, void* d_ws, size_t ws_size,
                              hipStream_t stream) {
    const float* user_emb = (const float*)d_in[0];
    const float* item_emb = (const float*)d_in[1];
    const int*   adj_src  = (const int*)d_in[2];
    const int*   adj_dst  = (const int*)d_in[3];
    const float* adj_vals = (const float*)d_in[4];
    const float* noise    = (const float*)d_in[5];
    const int E = in_sizes[2];

    const long long ND = (long long)NN * DIM;
    float* out_final = (float*)d_out;       // [NN, D] final
    float* out_cl    = out_final + ND;      // [NN, D] cl (also ego after layer 1)

    // workspace layout (~78 MB). ego_a aliases the pass-A bucketed records:
    // ssv_b is dead after bsort_k, before ego_a's first write (layer-2 spmm).
    char*  w       = (char*)d_ws;
    float* ego_a   = (float*)w;                          // ND floats (51.2 MB)
    int2*  ssv_b   = (int2*)w;                           // E records (25.6 MB), aliased
    int2*  ssv     = (int2*)(w + ND * sizeof(float));    // E records (25.6 MB)
    int*   bhist   = (int*)(ssv + E);                    // NB
    int*   bbase   = bhist + NB;                         // NB + 1
    int*   boff    = bbase + NB + 1;                     // NB
    int*   row_ptr = boff + NB;                          // NN + 1

    const int nchunk = (E + CH - 1) / CH;

    hipMemsetAsync(bhist, 0, NB * sizeof(int), stream);
    bhist_k<<<nchunk, 256, 0, stream>>>(adj_dst, bhist, E);
    bscan_k<<<1, 256, 0, stream>>>(bhist, bbase, boff, row_ptr, E);
    apart_k<<<nchunk, 256, 0, stream>>>(adj_src, adj_dst, adj_vals, boff, ssv_b, E);
    bsort_k<<<NB, 256, 0, stream>>>(bbase, ssv_b, ssv, row_ptr);

    const int spmm_grid = NN / 4;   // 200000 waves, one per dst row
    const float* item_shift = item_emb - (long long)USER_NUM * DIM;
    // layer 1: virtual concat(user,item) -> out_cl (doubles as cl), acc = val
    spmm_fused_k<<<spmm_grid, 256, 0, stream>>>(row_ptr, ssv, user_emb, item_shift,
                                                out_cl, noise, out_final, 1, 0);
    // layer 2: out_cl -> ego_a, acc += val
    spmm_fused_k<<<spmm_grid, 256, 0, stream>>>(row_ptr, ssv, out_cl, out_cl,
                                                ego_a, noise + ND, out_final, 0, 0);
    // layer 3: ego_a -> (no ego write), acc = (acc + val)/3
    spmm_fused_k<<<spmm_grid, 256, 0, stream>>>(row_ptr, ssv, ego_a, ego_a,
                                                nullptr, noise + 2 * ND, out_final, 0, 1);
}

// Round 4
// 778.651 us; speedup vs baseline: 1.0195x; 1.0195x over previous
//
#include <hip/hip_runtime.h>

#define USER_NUM 100000
#define ITEM_NUM 100000
#define NN 200000
#define DIM 64
#define EPSV 0.2f

#define NB 196          // coarse buckets of 1024 dst-nodes (ceil(200000/1024))
#define BSH 10          // bucket = dst >> 10
#define NPB 1024        // nodes per bucket
#define CH 4096         // edges per workgroup chunk in pass A
#define PER 16          // edges per thread (256*16 = 4096)
#define SRC_MASK 0x3FFFF

// ---------------------------------------------------------------------------
// K1: coarse bucket histogram (196 counters) via LDS aggregation
// ---------------------------------------------------------------------------
__global__ __launch_bounds__(256) void bhist_k(const int* __restrict__ dst,
                                               int* __restrict__ bhist, int E) {
    __shared__ int h[NB];
    int t = threadIdx.x;
    for (int i = t; i < NB; i += 256) h[i] = 0;
    __syncthreads();
    long long base = (long long)blockIdx.x * CH;
    #pragma unroll
    for (int j = 0; j < PER; ++j) {
        long long e = base + t + j * 256;
        if (e < E) atomicAdd(&h[dst[e] >> BSH], 1);
    }
    __syncthreads();
    for (int i = t; i < NB; i += 256) if (h[i]) atomicAdd(&bhist[i], h[i]);
}

// ---------------------------------------------------------------------------
// K2: exclusive scan over 196 bucket counts (single block)
// ---------------------------------------------------------------------------
__global__ __launch_bounds__(256) void bscan_k(const int* __restrict__ bhist,
                                               int* __restrict__ bucket_base,
                                               int* __restrict__ bucket_off,
                                               int* __restrict__ row_ptr, int E) {
    __shared__ int tmp[256];
    int t = threadIdx.x;
    int s = (t < NB) ? bhist[t] : 0;
    tmp[t] = s;
    __syncthreads();
    for (int off = 1; off < 256; off <<= 1) {
        int x = (t >= off) ? tmp[t - off] : 0;
        __syncthreads();
        tmp[t] += x;
        __syncthreads();
    }
    int excl = tmp[t] - s;
    if (t < NB) { bucket_base[t] = excl; bucket_off[t] = excl; }
    if (t == 0) { bucket_base[NB] = E; row_ptr[NN] = E; }
}

// ---------------------------------------------------------------------------
// K3 (pass A): LDS multi-split into 196 bucket regions, dense run writes.
// Record: x = src | (dst&1023)<<18 ; y = val bits.
// ---------------------------------------------------------------------------
__global__ __launch_bounds__(256) void apart_k(const int* __restrict__ src,
                                               const int* __restrict__ dst,
                                               const float* __restrict__ vals,
                                               int* __restrict__ bucket_off,
                                               int2* __restrict__ out, int E) {
    __shared__ int cnt[NB], start[NB], cursor[NB], gbase[NB];
    __shared__ int tmp[256];
    __shared__ int2 rec[CH];
    int t = threadIdx.x;
    long long base = (long long)blockIdx.x * CH;
    int nvalid = (int)min((long long)CH, (long long)E - base);

    int s_[PER]; int d_[PER]; float v_[PER];
    for (int i = t; i < NB; i += 256) cnt[i] = 0;
    __syncthreads();
    #pragma unroll
    for (int j = 0; j < PER; ++j) {
        int idx = t + j * 256;
        if (idx < nvalid) {
            long long e = base + idx;
            d_[j] = dst[e]; s_[j] = src[e]; v_[j] = vals[e];
            atomicAdd(&cnt[d_[j] >> BSH], 1);
        } else d_[j] = -1;
    }
    __syncthreads();
    int c = (t < NB) ? cnt[t] : 0;
    tmp[t] = c;
    __syncthreads();
    for (int off = 1; off < 256; off <<= 1) {
        int x = (t >= off) ? tmp[t - off] : 0;
        __syncthreads();
        tmp[t] += x;
        __syncthreads();
    }
    if (t < NB) {
        int excl = tmp[t] - c;
        start[t] = excl; cursor[t] = excl;
        gbase[t] = (c > 0) ? atomicAdd(&bucket_off[t], c) : 0;
    }
    __syncthreads();
    #pragma unroll
    for (int j = 0; j < PER; ++j) {
        if (d_[j] >= 0) {
            int b = d_[j] >> BSH;
            int slot = atomicAdd(&cursor[b], 1);
            rec[slot] = make_int2(s_[j] | ((d_[j] & (NPB - 1)) << 18),
                                  __float_as_int(v_[j]));
        }
    }
    __syncthreads();
    // flush: consecutive LDS slots -> contiguous global runs per bucket
    for (int slot = t; slot < nvalid; slot += 256) {
        int lo = 0, hi = NB - 1;
        while (lo < hi) {
            int mid = (lo + hi + 1) >> 1;
            if (start[mid] <= slot) lo = mid; else hi = mid - 1;
        }
        out[gbase[lo] + (slot - start[lo])] = rec[slot];
    }
}

// ---------------------------------------------------------------------------
// K4 (pass B): one WG per bucket. Per-node hist + scan in LDS -> row_ptr,
// then scatter to final CSR position (random only within ~130KB, 1 CU).
// ---------------------------------------------------------------------------
__global__ __launch_bounds__(256) void bsort_k(const int* __restrict__ bucket_base,
                                               const int2* __restrict__ in,
                                               int2* __restrict__ out,
                                               int* __restrict__ row_ptr) {
    __shared__ int noff[NPB];
    __shared__ int tmp[256];
    int b = blockIdx.x, t = threadIdx.x;
    int rbeg = bucket_base[b], rend = bucket_base[b + 1];
    for (int i = t; i < NPB; i += 256) noff[i] = 0;
    __syncthreads();
    for (int i = rbeg + t; i < rend; i += 256)
        atomicAdd(&noff[(in[i].x >> 18) & (NPB - 1)], 1);
    __syncthreads();
    // exclusive scan of 1024 counters with 256 threads (4 each)
    int l0 = noff[t * 4], l1 = noff[t * 4 + 1], l2 = noff[t * 4 + 2], l3 = noff[t * 4 + 3];
    int s = l0 + l1 + l2 + l3;
    tmp[t] = s;
    __syncthreads();
    for (int off = 1; off < 256; off <<= 1) {
        int x = (t >= off) ? tmp[t - off] : 0;
        __syncthreads();
        tmp[t] += x;
        __syncthreads();
    }
    int run = rbeg + tmp[t] - s;
    int e0 = run, e1 = run + l0, e2 = e1 + l1, e3 = e2 + l2;
    noff[t * 4] = e0; noff[t * 4 + 1] = e1; noff[t * 4 + 2] = e2; noff[t * 4 + 3] = e3;
    int node0 = b * NPB + t * 4;
    if (node0 < NN)     row_ptr[node0]     = e0;
    if (node0 + 1 < NN) row_ptr[node0 + 1] = e1;
    if (node0 + 2 < NN) row_ptr[node0 + 2] = e2;
    if (node0 + 3 < NN) row_ptr[node0 + 3] = e3;
    __syncthreads();
    for (int i = rbeg + t; i < rend; i += 256) {
        int2 r = in[i];
        int pos = atomicAdd(&noff[(r.x >> 18) & (NPB - 1)], 1);
        out[pos] = r;
    }
}

// RNE f32 -> bf16 pack (two floats -> one uint, low half = first)
__device__ __forceinline__ unsigned int bpack(float a, float b) {
    unsigned int ua = __float_as_uint(a), ub = __float_as_uint(b);
    ua = (ua + 0x7fffu + ((ua >> 16) & 1u)) >> 16;
    ub = (ub + 0x7fffu + ((ub >> 16) & 1u)) >> 16;
    return ua | (ub << 16);
}

// ---------------------------------------------------------------------------
// K0: convert concat(user_emb, item_emb) f32 -> bf16 table [NN][64]
// (runs after bsort_k; its output aliases the dead pass-A buffer)
// ---------------------------------------------------------------------------
__global__ __launch_bounds__(256) void cvt_k(const float* __restrict__ ue,
                                             const float* __restrict__ ie,
                                             unsigned int* __restrict__ out) {
    long long i = (long long)blockIdx.x * 256 + threadIdx.x;   // float4 index
    const long long tot = (long long)NN * (DIM / 4);           // 3.2M
    if (i >= tot) return;
    const long long uu = (long long)USER_NUM * (DIM / 4);
    const float4 v = (i < uu) ? reinterpret_cast<const float4*>(ue)[i]
                              : reinterpret_cast<const float4*>(ie)[i - uu];
    uint2 p; p.x = bpack(v.x, v.y); p.y = bpack(v.z, v.w);
    reinterpret_cast<uint2*>(out)[i] = p;
}

// ---------------------------------------------------------------------------
// fused segmented SpMM + noise injection + acc.
// one 64-lane wave per dst row; 4 edge-groups x 16 lanes.
// GATHER IS bf16: ego rows are 128B (2 cachelines, was 4) -- the round-3
// counters showed a ~2.7 TB/s L3/fabric service floor on gather misses, so
// halving bytes+lines is the lever. Lane reads uint2 (4 bf16 dims).
// f64 accumulation for replay-stability (CSR edge order varies across graph
// replays; sign() is discontinuous -- round-1 failure). bf16 quantization is
// deterministic, so replay-stability is unaffected.
// Epilogue: ego_out written as bf16 (next layer's gather), cl/acc exact f32.
// ---------------------------------------------------------------------------
__global__ __launch_bounds__(256) void spmm_fused_k(const int* __restrict__ row_ptr,
                                                    const int2* __restrict__ ssv,
                                                    const unsigned int* __restrict__ ego,
                                                    unsigned int* __restrict__ ego_out,
                                                    float* __restrict__ cl_out,
                                                    const float* __restrict__ nz_layer,
                                                    float* __restrict__ acc,
                                                    int is_first, int is_last) {
    int node = blockIdx.x * 4 + (threadIdx.x >> 6);
    int lane = threadIdx.x & 63;
    int g    = lane >> 4;           // edge slot 0..3 within a 4-edge block
    int d4   = lane & 15;           // which 4-dim chunk of the 64 dims
    int beg = row_ptr[node];
    int end = row_ptr[node + 1];

    double ax = 0.0, ay = 0.0, az = 0.0, aw = 0.0;
    int base = beg;

    // 16 edges per superiteration: 4 independent record loads, then 4
    // independent uint2 gathers in flight, then 16 f64 FMAs.
    for (; base + 16 <= end; base += 16) {
        int2 sv0 = ssv[base + g];
        int2 sv1 = ssv[base + 4 + g];
        int2 sv2 = ssv[base + 8 + g];
        int2 sv3 = ssv[base + 12 + g];
        int s0 = sv0.x & SRC_MASK, s1 = sv1.x & SRC_MASK;
        int s2 = sv2.x & SRC_MASK, s3 = sv3.x & SRC_MASK;
        const uint2 q0 = *reinterpret_cast<const uint2*>(ego + ((size_t)s0 << 5) + (d4 << 1));
        const uint2 q1 = *reinterpret_cast<const uint2*>(ego + ((size_t)s1 << 5) + (d4 << 1));
        const uint2 q2 = *reinterpret_cast<const uint2*>(ego + ((size_t)s2 << 5) + (d4 << 1));
        const uint2 q3 = *reinterpret_cast<const uint2*>(ego + ((size_t)s3 << 5) + (d4 << 1));
        double v0 = (double)__int_as_float(sv0.y);
        double v1 = (double)__int_as_float(sv1.y);
        double v2 = (double)__int_as_float(sv2.y);
        double v3 = (double)__int_as_float(sv3.y);
        float f0, f1, f2, f3;
        f0 = __uint_as_float(q0.x << 16); f1 = __uint_as_float(q0.x & 0xffff0000u);
        f2 = __uint_as_float(q0.y << 16); f3 = __uint_as_float(q0.y & 0xffff0000u);
        ax = fma((double)f0, v0, ax); ay = fma((double)f1, v0, ay);
        az = fma((double)f2, v0, az); aw = fma((double)f3, v0, aw);
        f0 = __uint_as_float(q1.x << 16); f1 = __uint_as_float(q1.x & 0xffff0000u);
        f2 = __uint_as_float(q1.y << 16); f3 = __uint_as_float(q1.y & 0xffff0000u);
        ax = fma((double)f0, v1, ax); ay = fma((double)f1, v1, ay);
        az = fma((double)f2, v1, az); aw = fma((double)f3, v1, aw);
        f0 = __uint_as_float(q2.x << 16); f1 = __uint_as_float(q2.x & 0xffff0000u);
        f2 = __uint_as_float(q2.y << 16); f3 = __uint_as_float(q2.y & 0xffff0000u);
        ax = fma((double)f0, v2, ax); ay = fma((double)f1, v2, ay);
        az = fma((double)f2, v2, az); aw = fma((double)f3, v2, aw);
        f0 = __uint_as_float(q3.x << 16); f1 = __uint_as_float(q3.x & 0xffff0000u);
        f2 = __uint_as_float(q3.y << 16); f3 = __uint_as_float(q3.y & 0xffff0000u);
        ax = fma((double)f0, v3, ax); ay = fma((double)f1, v3, ay);
        az = fma((double)f2, v3, az); aw = fma((double)f3, v3, aw);
    }
    for (; base + 4 <= end; base += 4) {
        int2 sv = ssv[base + g];
        int s = sv.x & SRC_MASK;
        double v = (double)__int_as_float(sv.y);
        const uint2 q = *reinterpret_cast<const uint2*>(ego + ((size_t)s << 5) + (d4 << 1));
        float f0 = __uint_as_float(q.x << 16), f1 = __uint_as_float(q.x & 0xffff0000u);
        float f2 = __uint_as_float(q.y << 16), f3 = __uint_as_float(q.y & 0xffff0000u);
        ax = fma((double)f0, v, ax); ay = fma((double)f1, v, ay);
        az = fma((double)f2, v, az); aw = fma((double)f3, v, aw);
    }
    int rem = end - base;
    if (g < rem) {
        int2 sv = ssv[base + g];
        int s = sv.x & SRC_MASK;
        double v = (double)__int_as_float(sv.y);
        const uint2 q = *reinterpret_cast<const uint2*>(ego + ((size_t)s << 5) + (d4 << 1));
        float f0 = __uint_as_float(q.x << 16), f1 = __uint_as_float(q.x & 0xffff0000u);
        float f2 = __uint_as_float(q.y << 16), f3 = __uint_as_float(q.y & 0xffff0000u);
        ax = fma((double)f0, v, ax); ay = fma((double)f1, v, ay);
        az = fma((double)f2, v, az); aw = fma((double)f3, v, aw);
    }
    // reduce the 4 edge groups (lane bits 4 and 5) in f64 (fixed tree order)
    ax += __shfl_xor(ax, 16, 64); ay += __shfl_xor(ay, 16, 64);
    az += __shfl_xor(az, 16, 64); aw += __shfl_xor(aw, 16, 64);
    ax += __shfl_xor(ax, 32, 64); ay += __shfl_xor(ay, 32, 64);
    az += __shfl_xor(az, 32, 64); aw += __shfl_xor(aw, 32, 64);
    float fx = (float)ax, fy = (float)ay, fz = (float)az, fw = (float)aw;

    size_t off = (size_t)node * DIM + (d4 << 2);
    const float4 nz = *reinterpret_cast<const float4*>(nz_layer + off);
    float ss = nz.x * nz.x + nz.y * nz.y + nz.z * nz.z + nz.w * nz.w;
    // reduce over the 16 dim-chunk lanes (groups hold identical copies)
    ss += __shfl_xor(ss, 1, 64);
    ss += __shfl_xor(ss, 2, 64);
    ss += __shfl_xor(ss, 4, 64);
    ss += __shfl_xor(ss, 8, 64);
    float e = EPSV / fmaxf(sqrtf(ss), 1e-12f);

    float4 val;
    val.x = fx + ((fx > 0.f) ? 1.f : ((fx < 0.f) ? -1.f : 0.f)) * nz.x * e;
    val.y = fy + ((fy > 0.f) ? 1.f : ((fy < 0.f) ? -1.f : 0.f)) * nz.y * e;
    val.z = fz + ((fz > 0.f) ? 1.f : ((fz < 0.f) ? -1.f : 0.f)) * nz.z * e;
    val.w = fw + ((fw > 0.f) ? 1.f : ((fw < 0.f) ? -1.f : 0.f)) * nz.w * e;

    if (g == 0) {
        if (!is_last) {
            uint2 p; p.x = bpack(val.x, val.y); p.y = bpack(val.z, val.w);
            *reinterpret_cast<uint2*>(ego_out + ((size_t)node << 5) + (d4 << 1)) = p;
        }
        if (cl_out) *reinterpret_cast<float4*>(cl_out + off) = val;
        float4 r4;
        if (is_first) {
            r4 = val;
        } else {
            const float4 p = *reinterpret_cast<const float4*>(acc + off);
            r4.x = p.x + val.x; r4.y = p.y + val.y;
            r4.z = p.z + val.z; r4.w = p.w + val.w;
        }
        if (is_last) {
            r4.x *= (1.0f / 3.0f); r4.y *= (1.0f / 3.0f);
            r4.z *= (1.0f / 3.0f); r4.w *= (1.0f / 3.0f);
        }
        *reinterpret_cast<float4*>(acc + off) = r4;
    }
}

extern "C" void kernel_launch(void* const* d_in, const int* in_sizes, int n_in,
                              void* d_out, int out_size, void* d_ws, size_t ws_size,
                              hipStream_t stream) {
    const float* user_emb = (const float*)d_in[0];
    const float* item_emb = (const float*)d_in[1];
    const int*   adj_src  = (const int*)d_in[2];
    const int*   adj_dst  = (const int*)d_in[3];
    const float* adj_vals = (const float*)d_in[4];
    const float* noise    = (const float*)d_in[5];
    const int E = in_sizes[2];

    const long long ND = (long long)NN * DIM;
    float* out_final = (float*)d_out;       // [NN, D] final
    float* out_cl    = out_final + ND;      // [NN, D] cl

    // workspace layout (~77.6 MB):
    //  [0, 25.6MB)      ssv_b (pass-A temp), later aliased by egoB0 (bf16 table)
    //  [25.6, 51.2MB)   egoB1 (bf16 ego, layer-1 output)
    //  [51.2, 76.8MB)   ssv (final CSR records)
    //  [76.8MB, ...)    bhist / bbase / boff / row_ptr
    char* w = (char*)d_ws;
    const long long B16 = (long long)NN * (DIM / 2) * 4;   // 25.6 MB
    unsigned int* egoB0 = (unsigned int*)w;                 // aliases ssv_b
    int2*         ssv_b = (int2*)w;
    unsigned int* egoB1 = (unsigned int*)(w + B16);
    int2*         ssv   = (int2*)(w + 2 * B16);
    int*   bhist   = (int*)(w + 3 * B16);
    int*   bbase   = bhist + NB;                            // NB + 1
    int*   boff    = bbase + NB + 1;                        // NB
    int*   row_ptr = boff + NB;                             // NN + 1

    const int nchunk = (E + CH - 1) / CH;

    hipMemsetAsync(bhist, 0, NB * sizeof(int), stream);
    bhist_k<<<nchunk, 256, 0, stream>>>(adj_dst, bhist, E);
    bscan_k<<<1, 256, 0, stream>>>(bhist, bbase, boff, row_ptr, E);
    apart_k<<<nchunk, 256, 0, stream>>>(adj_src, adj_dst, adj_vals, boff, ssv_b, E);
    bsort_k<<<NB, 256, 0, stream>>>(bbase, ssv_b, ssv, row_ptr);
    // ssv_b dead -> egoB0 safe to write
    cvt_k<<<(int)(((long long)NN * (DIM / 4) + 255) / 256), 256, 0, stream>>>(
        user_emb, item_emb, egoB0);

    const int spmm_grid = NN / 4;   // 200000 waves, one per dst row
    // layer 1: gather egoB0 -> ego egoB1 (bf16) + cl (f32) ; acc = val
    spmm_fused_k<<<spmm_grid, 256, 0, stream>>>(row_ptr, ssv, egoB0, egoB1,
                                                out_cl, noise, out_final, 1, 0);
    // layer 2: gather egoB1 -> egoB0 (bf16) ; acc += val
    spmm_fused_k<<<spmm_grid, 256, 0, stream>>>(row_ptr, ssv, egoB1, egoB0,
                                                nullptr, noise + ND, out_final, 0, 0);
    // layer 3: gather egoB0 -> (none) ; acc = (acc + val)/3
    spmm_fused_k<<<spmm_grid, 256, 0, stream>>>(row_ptr, ssv, egoB0, nullptr,
                                                nullptr, noise + 2 * ND, out_final, 0, 1);
}

// Round 5
// 748.109 us; speedup vs baseline: 1.0611x; 1.0408x over previous
//
#include <hip/hip_runtime.h>

#define USER_NUM 100000
#define ITEM_NUM 100000
#define NN 200000
#define DIM 64
#define EPSV 0.2f

#define NB 196          // coarse buckets of 1024 dst-nodes (ceil(200000/1024))
#define BSH 10          // bucket = dst >> 10
#define NPB 1024        // nodes per bucket
#define CH 4096         // edges per workgroup chunk in pass A
#define PER 16          // edges per thread (256*16 = 4096)
#define SRC_MASK 0x3FFFF

// ---------------------------------------------------------------------------
// K1: coarse bucket histogram (196 counters) via LDS aggregation
// ---------------------------------------------------------------------------
__global__ __launch_bounds__(256) void bhist_k(const int* __restrict__ dst,
                                               int* __restrict__ bhist, int E) {
    __shared__ int h[NB];
    int t = threadIdx.x;
    for (int i = t; i < NB; i += 256) h[i] = 0;
    __syncthreads();
    long long base = (long long)blockIdx.x * CH;
    #pragma unroll
    for (int j = 0; j < PER; ++j) {
        long long e = base + t + j * 256;
        if (e < E) atomicAdd(&h[dst[e] >> BSH], 1);
    }
    __syncthreads();
    for (int i = t; i < NB; i += 256) if (h[i]) atomicAdd(&bhist[i], h[i]);
}

// ---------------------------------------------------------------------------
// K2: exclusive scan over 196 bucket counts (single block)
// ---------------------------------------------------------------------------
__global__ __launch_bounds__(256) void bscan_k(const int* __restrict__ bhist,
                                               int* __restrict__ bucket_base,
                                               int* __restrict__ bucket_off,
                                               int* __restrict__ row_ptr, int E) {
    __shared__ int tmp[256];
    int t = threadIdx.x;
    int s = (t < NB) ? bhist[t] : 0;
    tmp[t] = s;
    __syncthreads();
    for (int off = 1; off < 256; off <<= 1) {
        int x = (t >= off) ? tmp[t - off] : 0;
        __syncthreads();
        tmp[t] += x;
        __syncthreads();
    }
    int excl = tmp[t] - s;
    if (t < NB) { bucket_base[t] = excl; bucket_off[t] = excl; }
    if (t == 0) { bucket_base[NB] = E; row_ptr[NN] = E; }
}

// ---------------------------------------------------------------------------
// K3 (pass A): LDS multi-split into 196 bucket regions, dense run writes.
// Record: x = src | (dst&1023)<<18 ; y = val bits.
// ---------------------------------------------------------------------------
__global__ __launch_bounds__(256) void apart_k(const int* __restrict__ src,
                                               const int* __restrict__ dst,
                                               const float* __restrict__ vals,
                                               int* __restrict__ bucket_off,
                                               int2* __restrict__ out, int E) {
    __shared__ int cnt[NB], start[NB], cursor[NB], gbase[NB];
    __shared__ int tmp[256];
    __shared__ int2 rec[CH];
    int t = threadIdx.x;
    long long base = (long long)blockIdx.x * CH;
    int nvalid = (int)min((long long)CH, (long long)E - base);

    int s_[PER]; int d_[PER]; float v_[PER];
    for (int i = t; i < NB; i += 256) cnt[i] = 0;
    __syncthreads();
    #pragma unroll
    for (int j = 0; j < PER; ++j) {
        int idx = t + j * 256;
        if (idx < nvalid) {
            long long e = base + idx;
            d_[j] = dst[e]; s_[j] = src[e]; v_[j] = vals[e];
            atomicAdd(&cnt[d_[j] >> BSH], 1);
        } else d_[j] = -1;
    }
    __syncthreads();
    int c = (t < NB) ? cnt[t] : 0;
    tmp[t] = c;
    __syncthreads();
    for (int off = 1; off < 256; off <<= 1) {
        int x = (t >= off) ? tmp[t - off] : 0;
        __syncthreads();
        tmp[t] += x;
        __syncthreads();
    }
    if (t < NB) {
        int excl = tmp[t] - c;
        start[t] = excl; cursor[t] = excl;
        gbase[t] = (c > 0) ? atomicAdd(&bucket_off[t], c) : 0;
    }
    __syncthreads();
    #pragma unroll
    for (int j = 0; j < PER; ++j) {
        if (d_[j] >= 0) {
            int b = d_[j] >> BSH;
            int slot = atomicAdd(&cursor[b], 1);
            rec[slot] = make_int2(s_[j] | ((d_[j] & (NPB - 1)) << 18),
                                  __float_as_int(v_[j]));
        }
    }
    __syncthreads();
    // flush: consecutive LDS slots -> contiguous global runs per bucket
    for (int slot = t; slot < nvalid; slot += 256) {
        int lo = 0, hi = NB - 1;
        while (lo < hi) {
            int mid = (lo + hi + 1) >> 1;
            if (start[mid] <= slot) lo = mid; else hi = mid - 1;
        }
        out[gbase[lo] + (slot - start[lo])] = rec[slot];
    }
}

// ---------------------------------------------------------------------------
// K4 (pass B): one WG per bucket. Per-node hist + scan in LDS -> row_ptr,
// then scatter to final CSR position (random only within ~130KB, 1 CU).
// ---------------------------------------------------------------------------
__global__ __launch_bounds__(256) void bsort_k(const int* __restrict__ bucket_base,
                                               const int2* __restrict__ in,
                                               int2* __restrict__ out,
                                               int* __restrict__ row_ptr) {
    __shared__ int noff[NPB];
    __shared__ int tmp[256];
    int b = blockIdx.x, t = threadIdx.x;
    int rbeg = bucket_base[b], rend = bucket_base[b + 1];
    for (int i = t; i < NPB; i += 256) noff[i] = 0;
    __syncthreads();
    for (int i = rbeg + t; i < rend; i += 256)
        atomicAdd(&noff[(in[i].x >> 18) & (NPB - 1)], 1);
    __syncthreads();
    // exclusive scan of 1024 counters with 256 threads (4 each)
    int l0 = noff[t * 4], l1 = noff[t * 4 + 1], l2 = noff[t * 4 + 2], l3 = noff[t * 4 + 3];
    int s = l0 + l1 + l2 + l3;
    tmp[t] = s;
    __syncthreads();
    for (int off = 1; off < 256; off <<= 1) {
        int x = (t >= off) ? tmp[t - off] : 0;
        __syncthreads();
        tmp[t] += x;
        __syncthreads();
    }
    int run = rbeg + tmp[t] - s;
    int e0 = run, e1 = run + l0, e2 = e1 + l1, e3 = e2 + l2;
    noff[t * 4] = e0; noff[t * 4 + 1] = e1; noff[t * 4 + 2] = e2; noff[t * 4 + 3] = e3;
    int node0 = b * NPB + t * 4;
    if (node0 < NN)     row_ptr[node0]     = e0;
    if (node0 + 1 < NN) row_ptr[node0 + 1] = e1;
    if (node0 + 2 < NN) row_ptr[node0 + 2] = e2;
    if (node0 + 3 < NN) row_ptr[node0 + 3] = e3;
    __syncthreads();
    for (int i = rbeg + t; i < rend; i += 256) {
        int2 r = in[i];
        int pos = atomicAdd(&noff[(r.x >> 18) & (NPB - 1)], 1);
        out[pos] = r;
    }
}

// RNE f32 -> bf16 pack (two floats -> one uint, low half = first)
__device__ __forceinline__ unsigned int bpack(float a, float b) {
    unsigned int ua = __float_as_uint(a), ub = __float_as_uint(b);
    ua = (ua + 0x7fffu + ((ua >> 16) & 1u)) >> 16;
    ub = (ub + 0x7fffu + ((ub >> 16) & 1u)) >> 16;
    return ua | (ub << 16);
}

__device__ __forceinline__ float bsign(float x) {
    return (x > 0.f) ? 1.f : ((x < 0.f) ? -1.f : 0.f);
}

// ---------------------------------------------------------------------------
// K0: convert concat(user_emb, item_emb) f32 -> bf16 table [NN][64]
// ---------------------------------------------------------------------------
__global__ __launch_bounds__(256) void cvt_k(const float* __restrict__ ue,
                                             const float* __restrict__ ie,
                                             unsigned int* __restrict__ out) {
    long long i = (long long)blockIdx.x * 256 + threadIdx.x;   // float4 index
    const long long tot = (long long)NN * (DIM / 4);           // 3.2M
    if (i >= tot) return;
    const long long uu = (long long)USER_NUM * (DIM / 4);
    const float4 v = (i < uu) ? reinterpret_cast<const float4*>(ue)[i]
                              : reinterpret_cast<const float4*>(ie)[i - uu];
    uint2 p; p.x = bpack(v.x, v.y); p.y = bpack(v.z, v.w);
    reinterpret_cast<uint2*>(out)[i] = p;
}

// unpack a uint4 (8 bf16) and fma into the 8 f64 accumulators
#define FMA8(q, vv)                                                          \
    do {                                                                     \
        float t0 = __uint_as_float((q).x << 16);                             \
        float t1 = __uint_as_float((q).x & 0xffff0000u);                     \
        float t2 = __uint_as_float((q).y << 16);                             \
        float t3 = __uint_as_float((q).y & 0xffff0000u);                     \
        float t4 = __uint_as_float((q).z << 16);                             \
        float t5 = __uint_as_float((q).z & 0xffff0000u);                     \
        float t6 = __uint_as_float((q).w << 16);                             \
        float t7 = __uint_as_float((q).w & 0xffff0000u);                     \
        a0 = fma((double)t0, (vv), a0); a1 = fma((double)t1, (vv), a1);      \
        a2 = fma((double)t2, (vv), a2); a3 = fma((double)t3, (vv), a3);      \
        a4 = fma((double)t4, (vv), a4); a5 = fma((double)t5, (vv), a5);      \
        a6 = fma((double)t6, (vv), a6); a7 = fma((double)t7, (vv), a7);      \
    } while (0)

// ---------------------------------------------------------------------------
// fused segmented SpMM + noise injection + acc.
// one 64-lane wave per dst row. NEW: 8 edge-groups x 8 lanes; each lane
// gathers uint4 = 8 bf16 dims, so ONE scattered instruction covers 8 edges
// (was 4) -- round-4 counters showed time tracks scattered-VMEM instruction
// count, not bytes/lines (FETCH halved, dur -6%). Main-loop VMEM instr/edge
// drops 0.5 -> 0.25 at identical traffic.
// f64 accumulation for replay-stability (CSR edge order varies across graph
// replays; sign() is discontinuous -- round-1 failure).
// ---------------------------------------------------------------------------
__global__ __launch_bounds__(256) void spmm_fused_k(const int* __restrict__ row_ptr,
                                                    const int2* __restrict__ ssv,
                                                    const unsigned int* __restrict__ ego,
                                                    unsigned int* __restrict__ ego_out,
                                                    float* __restrict__ cl_out,
                                                    const float* __restrict__ nz_layer,
                                                    float* __restrict__ acc,
                                                    int is_first, int is_last) {
    int node = blockIdx.x * 4 + (threadIdx.x >> 6);
    int lane = threadIdx.x & 63;
    int g    = lane >> 3;           // edge slot 0..7 within an 8-edge block
    int d8   = lane & 7;            // which 8-dim chunk of the 64 dims
    int beg = row_ptr[node];
    int end = row_ptr[node + 1];

    double a0 = 0, a1 = 0, a2 = 0, a3 = 0, a4 = 0, a5 = 0, a6 = 0, a7 = 0;
    int base = beg;

    // 16 edges per superiteration: 2 independent {record, uint4 gather} chains
    for (; base + 16 <= end; base += 16) {
        int2 svA = ssv[base + g];
        int2 svB = ssv[base + 8 + g];
        int sA = svA.x & SRC_MASK;
        int sB = svB.x & SRC_MASK;
        const uint4 qA = *reinterpret_cast<const uint4*>(ego + ((size_t)sA << 5) + (d8 << 2));
        const uint4 qB = *reinterpret_cast<const uint4*>(ego + ((size_t)sB << 5) + (d8 << 2));
        double vA = (double)__int_as_float(svA.y);
        double vB = (double)__int_as_float(svB.y);
        FMA8(qA, vA);
        FMA8(qB, vB);
    }
    if (base + 8 <= end) {
        int2 sv = ssv[base + g];
        int s = sv.x & SRC_MASK;
        const uint4 q = *reinterpret_cast<const uint4*>(ego + ((size_t)s << 5) + (d8 << 2));
        double v = (double)__int_as_float(sv.y);
        FMA8(q, v);
        base += 8;
    }
    int rem = end - base;
    if (rem > 0) {
        int2 sv = ssv[base + ((g < rem) ? g : 0)];
        int s = sv.x & SRC_MASK;
        const uint4 q = *reinterpret_cast<const uint4*>(ego + ((size_t)s << 5) + (d8 << 2));
        double v = (g < rem) ? (double)__int_as_float(sv.y) : 0.0;
        FMA8(q, v);
    }

    // reduce the 8 edge groups (lane bits 3,4,5), fixed deterministic order
    a0 += __shfl_xor(a0, 8, 64);  a1 += __shfl_xor(a1, 8, 64);
    a2 += __shfl_xor(a2, 8, 64);  a3 += __shfl_xor(a3, 8, 64);
    a4 += __shfl_xor(a4, 8, 64);  a5 += __shfl_xor(a5, 8, 64);
    a6 += __shfl_xor(a6, 8, 64);  a7 += __shfl_xor(a7, 8, 64);
    a0 += __shfl_xor(a0, 16, 64); a1 += __shfl_xor(a1, 16, 64);
    a2 += __shfl_xor(a2, 16, 64); a3 += __shfl_xor(a3, 16, 64);
    a4 += __shfl_xor(a4, 16, 64); a5 += __shfl_xor(a5, 16, 64);
    a6 += __shfl_xor(a6, 16, 64); a7 += __shfl_xor(a7, 16, 64);
    a0 += __shfl_xor(a0, 32, 64); a1 += __shfl_xor(a1, 32, 64);
    a2 += __shfl_xor(a2, 32, 64); a3 += __shfl_xor(a3, 32, 64);
    a4 += __shfl_xor(a4, 32, 64); a5 += __shfl_xor(a5, 32, 64);
    a6 += __shfl_xor(a6, 32, 64); a7 += __shfl_xor(a7, 32, 64);

    float f0 = (float)a0, f1 = (float)a1, f2 = (float)a2, f3 = (float)a3;
    float f4 = (float)a4, f5 = (float)a5, f6 = (float)a6, f7 = (float)a7;

    size_t off = (size_t)node * DIM + (d8 << 3);
    const float4 n0 = *reinterpret_cast<const float4*>(nz_layer + off);
    const float4 n1 = *reinterpret_cast<const float4*>(nz_layer + off + 4);
    float ss = n0.x * n0.x + n0.y * n0.y + n0.z * n0.z + n0.w * n0.w
             + n1.x * n1.x + n1.y * n1.y + n1.z * n1.z + n1.w * n1.w;
    // reduce over the 8 dim-chunk lanes (edge groups hold identical copies)
    ss += __shfl_xor(ss, 1, 64);
    ss += __shfl_xor(ss, 2, 64);
    ss += __shfl_xor(ss, 4, 64);
    float e = EPSV / fmaxf(sqrtf(ss), 1e-12f);

    float w0 = f0 + bsign(f0) * n0.x * e;
    float w1 = f1 + bsign(f1) * n0.y * e;
    float w2 = f2 + bsign(f2) * n0.z * e;
    float w3 = f3 + bsign(f3) * n0.w * e;
    float w4 = f4 + bsign(f4) * n1.x * e;
    float w5 = f5 + bsign(f5) * n1.y * e;
    float w6 = f6 + bsign(f6) * n1.z * e;
    float w7 = f7 + bsign(f7) * n1.w * e;

    if (g == 0) {
        if (!is_last) {
            uint4 p;
            p.x = bpack(w0, w1); p.y = bpack(w2, w3);
            p.z = bpack(w4, w5); p.w = bpack(w6, w7);
            *reinterpret_cast<uint4*>(ego_out + ((size_t)node << 5) + (d8 << 2)) = p;
        }
        float4 v0 = make_float4(w0, w1, w2, w3);
        float4 v1 = make_float4(w4, w5, w6, w7);
        if (cl_out) {
            *reinterpret_cast<float4*>(cl_out + off)     = v0;
            *reinterpret_cast<float4*>(cl_out + off + 4) = v1;
        }
        float4 r0, r1;
        if (is_first) {
            r0 = v0; r1 = v1;
        } else {
            const float4 p0 = *reinterpret_cast<const float4*>(acc + off);
            const float4 p1 = *reinterpret_cast<const float4*>(acc + off + 4);
            r0.x = p0.x + v0.x; r0.y = p0.y + v0.y; r0.z = p0.z + v0.z; r0.w = p0.w + v0.w;
            r1.x = p1.x + v1.x; r1.y = p1.y + v1.y; r1.z = p1.z + v1.z; r1.w = p1.w + v1.w;
        }
        if (is_last) {
            const float k = 1.0f / 3.0f;
            r0.x *= k; r0.y *= k; r0.z *= k; r0.w *= k;
            r1.x *= k; r1.y *= k; r1.z *= k; r1.w *= k;
        }
        *reinterpret_cast<float4*>(acc + off)     = r0;
        *reinterpret_cast<float4*>(acc + off + 4) = r1;
    }
}

extern "C" void kernel_launch(void* const* d_in, const int* in_sizes, int n_in,
                              void* d_out, int out_size, void* d_ws, size_t ws_size,
                              hipStream_t stream) {
    const float* user_emb = (const float*)d_in[0];
    const float* item_emb = (const float*)d_in[1];
    const int*   adj_src  = (const int*)d_in[2];
    const int*   adj_dst  = (const int*)d_in[3];
    const float* adj_vals = (const float*)d_in[4];
    const float* noise    = (const float*)d_in[5];
    const int E = in_sizes[2];

    const long long ND = (long long)NN * DIM;
    float* out_final = (float*)d_out;       // [NN, D] final
    float* out_cl    = out_final + ND;      // [NN, D] cl

    // workspace layout (~77.6 MB):
    //  [0, 25.6MB)      ssv_b (pass-A temp), later aliased by egoB0 (bf16 table)
    //  [25.6, 51.2MB)   egoB1 (bf16 ego, layer-1 output)
    //  [51.2, 76.8MB)   ssv (final CSR records)
    //  [76.8MB, ...)    bhist / bbase / boff / row_ptr
    char* w = (char*)d_ws;
    const long long B16 = (long long)NN * (DIM / 2) * 4;   // 25.6 MB
    unsigned int* egoB0 = (unsigned int*)w;                 // aliases ssv_b
    int2*         ssv_b = (int2*)w;
    unsigned int* egoB1 = (unsigned int*)(w + B16);
    int2*         ssv   = (int2*)(w + 2 * B16);
    int*   bhist   = (int*)(w + 3 * B16);
    int*   bbase   = bhist + NB;                            // NB + 1
    int*   boff    = bbase + NB + 1;                        // NB
    int*   row_ptr = boff + NB;                             // NN + 1

    const int nchunk = (E + CH - 1) / CH;

    hipMemsetAsync(bhist, 0, NB * sizeof(int), stream);
    bhist_k<<<nchunk, 256, 0, stream>>>(adj_dst, bhist, E);
    bscan_k<<<1, 256, 0, stream>>>(bhist, bbase, boff, row_ptr, E);
    apart_k<<<nchunk, 256, 0, stream>>>(adj_src, adj_dst, adj_vals, boff, ssv_b, E);
    bsort_k<<<NB, 256, 0, stream>>>(bbase, ssv_b, ssv, row_ptr);
    // ssv_b dead -> egoB0 safe to write
    cvt_k<<<(int)(((long long)NN * (DIM / 4) + 255) / 256), 256, 0, stream>>>(
        user_emb, item_emb, egoB0);

    const int spmm_grid = NN / 4;   // 200000 waves, one per dst row
    // layer 1: gather egoB0 -> ego egoB1 (bf16) + cl (f32) ; acc = val
    spmm_fused_k<<<spmm_grid, 256, 0, stream>>>(row_ptr, ssv, egoB0, egoB1,
                                                out_cl, noise, out_final, 1, 0);
    // layer 2: gather egoB1 -> egoB0 (bf16) ; acc += val
    spmm_fused_k<<<spmm_grid, 256, 0, stream>>>(row_ptr, ssv, egoB1, egoB0,
                                                nullptr, noise + ND, out_final, 0, 0);
    // layer 3: gather egoB0 -> (none) ; acc = (acc + val)/3
    spmm_fused_k<<<spmm_grid, 256, 0, stream>>>(row_ptr, ssv, egoB0, nullptr,
                                                nullptr, noise + 2 * ND, out_final, 0, 1);
}